// Round 1
// baseline (464.024 us; speedup 1.0000x reference)
//
#include <hip/hip_runtime.h>
#include <hip/hip_bf16.h>

typedef __bf16 bf16_t;
typedef __attribute__((ext_vector_type(8))) __bf16 bf16x8;
typedef __attribute__((ext_vector_type(4))) __bf16 bf16x4;
typedef __attribute__((ext_vector_type(4))) float f32x4;

#define E_DIM 256
#define J_DIM 32
#define B_DIM 4096
#define M_DIM (B_DIM * J_DIM)

// fused prep kernel block ranges
#define XK_BLOCKS 512                    // blocks [0,512): xk
#define CVT_BLOCKS 64                    // [512,576): U->bf16, [576,640): W->bf16
#define VKB_BLOCKS 32                    // [640,672): vkb
#define PREP_GRID (XK_BLOCKS + 2 * CVT_BLOCKS + VKB_BLOCKS)

#define XK_LDA (E_DIM + 4)               // +4 floats: 32-way -> 4-way bank alias, keeps 16B align

// ---------------------------------------------------------------------------
// prep: xk[b][j] = <x_b, k_j> (fp32, LDS-padded)  |  U,W -> bf16  |  vkb[j][f]
// ---------------------------------------------------------------------------
__global__ __launch_bounds__(256) void prep_kernel(
    const float* __restrict__ x, const float* __restrict__ keys,
    const float* __restrict__ U, const float* __restrict__ V,
    const float* __restrict__ W, const float* __restrict__ bias,
    float* __restrict__ xk, float* __restrict__ vkb,
    bf16_t* __restrict__ Ubf, bf16_t* __restrict__ Wbf) {
    __shared__ float smem[(J_DIM + 8) * XK_LDA];   // 40*260 fp32 = 41.6 KB
    int tid = threadIdx.x;
    int bid = blockIdx.x;
    if (bid < XK_BLOCKS) {
        // xk: 8 b-rows per block, fp32 VALU dot
        float* sK = smem;                          // [32][XK_LDA]
        float* sX = smem + J_DIM * XK_LDA;         // [8][XK_LDA]
        int b0 = bid * 8;
#pragma unroll
        for (int it = 0; it < 8; ++it) {
            int t = it * 256 + tid;
            int r = t >> 6, c = (t & 63) * 4;
            *(f32x4*)(sK + r * XK_LDA + c) = *(const f32x4*)(keys + (size_t)r * E_DIM + c);
        }
#pragma unroll
        for (int it = 0; it < 2; ++it) {
            int t = it * 256 + tid;
            int r = t >> 6, c = (t & 63) * 4;
            *(f32x4*)(sX + r * XK_LDA + c) =
                *(const f32x4*)(x + (size_t)(b0 + r) * E_DIM + c);
        }
        __syncthreads();
        int j = tid & 31, bl = tid >> 5;
        float acc = 0.f;
        for (int e = 0; e < E_DIM; e += 4) {
            f32x4 xv = *(const f32x4*)(sX + bl * XK_LDA + e);
            f32x4 kv = *(const f32x4*)(sK + j * XK_LDA + e);
#pragma unroll
            for (int i = 0; i < 4; ++i) acc += xv[i] * kv[i];
        }
        xk[(size_t)(b0 + bl) * J_DIM + j] = acc;
    } else if (bid < XK_BLOCKS + 2 * CVT_BLOCKS) {
        // convert U / W to bf16 (RNE, same rounding as the old in-loop cvt8)
        int cb = bid - XK_BLOCKS;
        const float* src = (cb < CVT_BLOCKS) ? U : W;
        bf16_t* dst = (cb < CVT_BLOCKS) ? Ubf : Wbf;
        int idx = (cb & (CVT_BLOCKS - 1)) * 1024 + tid * 4;
        f32x4 v = *(const f32x4*)(src + idx);
        bf16x4 o;
#pragma unroll
        for (int i = 0; i < 4; ++i) o[i] = (bf16_t)v[i];
        *(bf16x4*)(dst + idx) = o;
    } else {
        // vkb[j][f] = bias[f] + sum_e V[f,e]*keys[j,e]
        int j = bid - (XK_BLOCKS + 2 * CVT_BLOCKS);
        int f = tid;
        float* sk = smem;
        sk[f] = keys[(size_t)j * E_DIM + f];
        __syncthreads();
        float acc = bias[f];
        for (int e = 0; e < E_DIM; e += 4) {
            f32x4 vv = *(const f32x4*)(V + (size_t)f * E_DIM + e);
#pragma unroll
            for (int i = 0; i < 4; ++i) acc += vv[i] * sk[e + i];
        }
        vkb[(size_t)j * E_DIM + f] = acc;
    }
}

// ---------------------------------------------------------------------------
// wx[b][f] = sum_e W[f,e]*x[b,e] — barrier-free MFMA, direct global fragments
// ---------------------------------------------------------------------------
__global__ __launch_bounds__(256) void wx_kernel(const float* __restrict__ x,
                                                 const bf16_t* __restrict__ Wbf,
                                                 float* __restrict__ wx) {
    int tid = threadIdx.x;
    int w = tid >> 6, lane = tid & 63, quad = lane >> 4, l15 = lane & 15;
    int m0 = blockIdx.x * 64;
    f32x4 acc[16];
#pragma unroll
    for (int nt = 0; nt < 16; ++nt)
#pragma unroll
        for (int r = 0; r < 4; ++r) acc[nt][r] = 0.f;
    const float* ap = x + (size_t)(m0 + w * 16 + l15) * E_DIM + quad * 8;
    const bf16_t* bp = Wbf + (size_t)l15 * E_DIM + quad * 8;
#pragma unroll
    for (int kc = 0; kc < 8; ++kc) {
        int k0 = kc * 32;
        f32x4 a0 = *(const f32x4*)(ap + k0);
        f32x4 a1 = *(const f32x4*)(ap + k0 + 4);
        bf16x8 af;
#pragma unroll
        for (int i = 0; i < 4; ++i) { af[i] = (bf16_t)a0[i]; af[4 + i] = (bf16_t)a1[i]; }
#pragma unroll
        for (int nt = 0; nt < 16; ++nt) {
            bf16x8 bfr = *(const bf16x8*)(bp + k0 + nt * 16 * E_DIM);
            acc[nt] = __builtin_amdgcn_mfma_f32_16x16x32_bf16(af, bfr, acc[nt], 0, 0, 0);
        }
    }
#pragma unroll
    for (int nt = 0; nt < 16; ++nt)
#pragma unroll
        for (int r = 0; r < 4; ++r)
            wx[(size_t)(m0 + w * 16 + quad * 4 + r) * E_DIM + nt * 16 + l15] = acc[nt][r];
}

// ---------------------------------------------------------------------------
// main: cand = s@U^T + wx[b] + vkb[j]; gate = sigmoid(<x,s>_fp32 + xk);
//       out = normalize(s + gate*relu(cand))
// Barrier-free: zero LDS. A-fragments (state) loaded straight from global
// (row = w*16+l15, k = quad*8..+8 is contiguous), one-deep prefetch.
// B-fragments read from pre-converted Ubf (128 KB, L1/L2-resident).
// Gate dot in fp32 from the same A registers + direct x loads (L1-hot).
// ---------------------------------------------------------------------------
__global__ __launch_bounds__(256) void memcell_kernel(
    const float* __restrict__ x, const float* __restrict__ state,
    const bf16_t* __restrict__ Ubf, const float* __restrict__ wx,
    const float* __restrict__ xk, const float* __restrict__ vkb,
    float* __restrict__ out) {
    int tid = threadIdx.x;
    int w = tid >> 6, lane = tid & 63, quad = lane >> 4, l15 = lane & 15;
    int m0 = blockIdx.x * 64;
    int bw = (m0 >> 5) + (w >> 1);            // one b per wave
    f32x4 acc[16];
#pragma unroll
    for (int nt = 0; nt < 16; ++nt)
#pragma unroll
        for (int r = 0; r < 4; ++r) acc[nt][r] = 0.f;
    float gdot = 0.f;
    const float* sp = state + (size_t)(m0 + w * 16 + l15) * E_DIM + quad * 8;
    const float* xp = x + (size_t)bw * E_DIM + quad * 8;
    const bf16_t* up = Ubf + (size_t)l15 * E_DIM + quad * 8;
    f32x4 a0 = *(const f32x4*)sp;
    f32x4 a1 = *(const f32x4*)(sp + 4);
#pragma unroll
    for (int kc = 0; kc < 8; ++kc) {
        int k0 = kc * 32;
        int kn = ((kc + 1) & 7) * 32;          // kc=7 wraps: harmless L1-hit reload
        f32x4 n0 = *(const f32x4*)(sp + kn);
        f32x4 n1 = *(const f32x4*)(sp + kn + 4);
        f32x4 xv0 = *(const f32x4*)(xp + k0);
        f32x4 xv1 = *(const f32x4*)(xp + k0 + 4);
        bf16x8 af;
#pragma unroll
        for (int i = 0; i < 4; ++i) { af[i] = (bf16_t)a0[i]; af[4 + i] = (bf16_t)a1[i]; }
#pragma unroll
        for (int i = 0; i < 4; ++i) gdot += a0[i] * xv0[i];
#pragma unroll
        for (int i = 0; i < 4; ++i) gdot += a1[i] * xv1[i];
#pragma unroll
        for (int nt = 0; nt < 16; ++nt) {
            bf16x8 bfr = *(const bf16x8*)(up + k0 + nt * 16 * E_DIM);
            acc[nt] = __builtin_amdgcn_mfma_f32_16x16x32_bf16(af, bfr, acc[nt], 0, 0, 0);
        }
        a0 = n0; a1 = n1;
    }
    // reduce gate dot across quads (k was split quad-wise)
    gdot += __shfl_xor(gdot, 16);
    gdot += __shfl_xor(gdot, 32);
    float garg = gdot + xk[(size_t)bw * J_DIM + (w & 1) * 16 + l15];
    float gv = 1.f / (1.f + expf(-garg));
    float gate[4];
#pragma unroll
    for (int r = 0; r < 4; ++r) gate[r] = __shfl(gv, quad * 4 + r);
    // epilogue: C/D layout row = quad*4+r, col = nt*16+l15
    float sumsq[4] = {0.f, 0.f, 0.f, 0.f};
    const float* wxrow = wx + (size_t)bw * E_DIM;
#pragma unroll
    for (int nt = 0; nt < 16; ++nt) {
        int f = nt * 16 + l15;
        float wxf = wxrow[f];
#pragma unroll
        for (int r = 0; r < 4; ++r) {
            int rl = quad * 4 + r;
            int jidx = (w & 1) * 16 + rl;
            float c = acc[nt][r] + wxf + vkb[(size_t)jidx * E_DIM + f];
            c = fmaxf(c, 0.f);
            float sv = state[(size_t)(m0 + w * 16 + rl) * E_DIM + f]; // LLC-hot re-read
            float t = fmaf(gate[r], c, sv);
            acc[nt][r] = t;
            sumsq[r] += t * t;
        }
    }
    float rn[4];
#pragma unroll
    for (int r = 0; r < 4; ++r) {
        float s2 = sumsq[r];
        s2 += __shfl_xor(s2, 1);
        s2 += __shfl_xor(s2, 2);
        s2 += __shfl_xor(s2, 4);
        s2 += __shfl_xor(s2, 8);
        rn[r] = 1.f / (sqrtf(s2) + 1e-8f);
    }
#pragma unroll
    for (int nt = 0; nt < 16; ++nt)
#pragma unroll
        for (int r = 0; r < 4; ++r)
            out[(size_t)(m0 + w * 16 + quad * 4 + r) * E_DIM + nt * 16 + l15] =
                acc[nt][r] * rn[r];
}

extern "C" void kernel_launch(void* const* d_in, const int* in_sizes, int n_in,
                              void* d_out, int out_size, void* d_ws, size_t ws_size,
                              hipStream_t stream) {
    const float* x     = (const float*)d_in[0];
    const float* state = (const float*)d_in[1];
    const float* keys  = (const float*)d_in[2];
    const float* U     = (const float*)d_in[3];
    const float* V     = (const float*)d_in[4];
    const float* W     = (const float*)d_in[5];
    const float* bias  = (const float*)d_in[6];
    float* out = (float*)d_out;

    float* wsf = (float*)d_ws;
    float* wx  = wsf;                                   // 4096*256 fp32 = 4 MB
    float* xk  = wsf + (size_t)B_DIM * E_DIM;           // 4096*32  fp32 = 512 KB
    float* vkb = xk + (size_t)B_DIM * J_DIM;            // 32*256   fp32 = 32 KB
    bf16_t* Ubf = (bf16_t*)(vkb + (size_t)J_DIM * E_DIM); // 256*256 bf16 = 128 KB
    bf16_t* Wbf = Ubf + (size_t)E_DIM * E_DIM;            // 256*256 bf16 = 128 KB

    prep_kernel<<<PREP_GRID, 256, 0, stream>>>(x, keys, U, V, W, bias, xk, vkb, Ubf, Wbf);
    wx_kernel<<<B_DIM / 64, 256, 0, stream>>>(x, Wbf, wx);
    memcell_kernel<<<M_DIM / 64, 256, 0, stream>>>(x, state, Ubf, wx, xk, vkb, out);
}

// Round 2
// 363.953 us; speedup vs baseline: 1.2750x; 1.2750x over previous
//
#include <hip/hip_runtime.h>
#include <hip/hip_bf16.h>

typedef __bf16 bf16_t;
typedef __attribute__((ext_vector_type(8))) __bf16 bf16x8;
typedef __attribute__((ext_vector_type(4))) __bf16 bf16x4;
typedef __attribute__((ext_vector_type(4))) float f32x4;

#define E_DIM 256
#define J_DIM 32
#define B_DIM 4096
#define M_DIM (B_DIM * J_DIM)

// fused prep kernel block ranges
#define XK_BLOCKS 512                    // blocks [0,512): xk
#define CVT_BLOCKS 64                    // [512,576): U->bf16, [576,640): W->bf16
#define VKB_BLOCKS 32                    // [640,672): vkb
#define PREP_GRID (XK_BLOCKS + 2 * CVT_BLOCKS + VKB_BLOCKS)

#define XK_LDA (E_DIM + 4)               // 32-way -> 4-way bank alias, keeps 16B align
#define LDB 40                           // bf16 row pad: 16B-aligned rows, <=2-way bank alias

// ---------------------------------------------------------------------------
// prep: xk[b][j] = <x_b, k_j> (fp32)  |  U,W -> bf16  |  vkb[j][f]
// ---------------------------------------------------------------------------
__global__ __launch_bounds__(256) void prep_kernel(
    const float* __restrict__ x, const float* __restrict__ keys,
    const float* __restrict__ U, const float* __restrict__ V,
    const float* __restrict__ W, const float* __restrict__ bias,
    float* __restrict__ xk, float* __restrict__ vkb,
    bf16_t* __restrict__ Ubf, bf16_t* __restrict__ Wbf) {
    __shared__ float smem[(J_DIM + 8) * XK_LDA];   // 40*260 fp32 = 41.6 KB
    int tid = threadIdx.x;
    int bid = blockIdx.x;
    if (bid < XK_BLOCKS) {
        float* sK = smem;                          // [32][XK_LDA]
        float* sX = smem + J_DIM * XK_LDA;         // [8][XK_LDA]
        int b0 = bid * 8;
#pragma unroll
        for (int it = 0; it < 8; ++it) {
            int t = it * 256 + tid;
            int r = t >> 6, c = (t & 63) * 4;
            *(f32x4*)(sK + r * XK_LDA + c) = *(const f32x4*)(keys + (size_t)r * E_DIM + c);
        }
#pragma unroll
        for (int it = 0; it < 2; ++it) {
            int t = it * 256 + tid;
            int r = t >> 6, c = (t & 63) * 4;
            *(f32x4*)(sX + r * XK_LDA + c) =
                *(const f32x4*)(x + (size_t)(b0 + r) * E_DIM + c);
        }
        __syncthreads();
        int j = tid & 31, bl = tid >> 5;
        float acc = 0.f;
        for (int e = 0; e < E_DIM; e += 4) {
            f32x4 xv = *(const f32x4*)(sX + bl * XK_LDA + e);
            f32x4 kv = *(const f32x4*)(sK + j * XK_LDA + e);
#pragma unroll
            for (int i = 0; i < 4; ++i) acc += xv[i] * kv[i];
        }
        xk[(size_t)(b0 + bl) * J_DIM + j] = acc;
    } else if (bid < XK_BLOCKS + 2 * CVT_BLOCKS) {
        int cb = bid - XK_BLOCKS;
        const float* src = (cb < CVT_BLOCKS) ? U : W;
        bf16_t* dst = (cb < CVT_BLOCKS) ? Ubf : Wbf;
        int idx = (cb & (CVT_BLOCKS - 1)) * 1024 + tid * 4;
        f32x4 v = *(const f32x4*)(src + idx);
        bf16x4 o;
#pragma unroll
        for (int i = 0; i < 4; ++i) o[i] = (bf16_t)v[i];
        *(bf16x4*)(dst + idx) = o;
    } else {
        int j = bid - (XK_BLOCKS + 2 * CVT_BLOCKS);
        int f = tid;
        float* sk = smem;
        sk[f] = keys[(size_t)j * E_DIM + f];
        __syncthreads();
        float acc = bias[f];
        for (int e = 0; e < E_DIM; e += 4) {
            f32x4 vv = *(const f32x4*)(V + (size_t)f * E_DIM + e);
#pragma unroll
            for (int i = 0; i < 4; ++i) acc += vv[i] * sk[e + i];
        }
        vkb[(size_t)j * E_DIM + f] = acc;
    }
}

// ---------------------------------------------------------------------------
// main, fused wx: augmented GEMM  cand = [s ; x] @ [U ; W]^T + vkb
//   K = 512 (kc 0..7: state part, kc 8..15: x part, A-row broadcast per b)
// A direct from global (line-coalesced per quad group), B double-buffered LDS
// (staged from pre-converted bf16, issue-early/write-late, 1 barrier per kc).
// Gate dot fp32 from the same global A regs. Epilogue unchanged (minus wx).
// ---------------------------------------------------------------------------
__global__ __launch_bounds__(256) void memcell_kernel(
    const float* __restrict__ x, const float* __restrict__ state,
    const bf16_t* __restrict__ Ubf, const bf16_t* __restrict__ Wbf,
    const float* __restrict__ xk, const float* __restrict__ vkb,
    float* __restrict__ out) {
    __shared__ __align__(16) bf16_t sB[2][E_DIM][LDB];   // 2 x 20 KB
    int tid = threadIdx.x;
    int w = tid >> 6, lane = tid & 63, quad = lane >> 4, l15 = lane & 15;
    int m0 = blockIdx.x * 64;
    int bw = (m0 >> 5) + (w >> 1);            // one b per wave
    f32x4 acc[16];
#pragma unroll
    for (int nt = 0; nt < 16; ++nt)
#pragma unroll
        for (int r = 0; r < 4; ++r) acc[nt][r] = 0.f;
    float gdot = 0.f;
    const float* sp = state + (size_t)(m0 + w * 16 + l15) * E_DIM + quad * 8;
    const float* xp = x + (size_t)bw * E_DIM + quad * 8;

    // prologue: stage kc=0 B-tile (U cols 0..31) + prefetch first A chunk
    bf16x8 br0, br1, br2, br3;
    {
        const bf16_t* bp = Ubf + (size_t)tid * E_DIM;
        br0 = *(const bf16x8*)(bp);
        br1 = *(const bf16x8*)(bp + 8);
        br2 = *(const bf16x8*)(bp + 16);
        br3 = *(const bf16x8*)(bp + 24);
    }
    f32x4 a0 = *(const f32x4*)sp;
    f32x4 a1 = *(const f32x4*)(sp + 4);
    *(bf16x8*)(&sB[0][tid][0])  = br0;
    *(bf16x8*)(&sB[0][tid][8])  = br1;
    *(bf16x8*)(&sB[0][tid][16]) = br2;
    *(bf16x8*)(&sB[0][tid][24]) = br3;
    __syncthreads();

#pragma unroll
    for (int kc = 0; kc < 16; ++kc) {
        const int cur = kc & 1;
        // issue next B-tile loads early (L2-resident bf16)
        if (kc < 15) {
            const int kn = kc + 1;
            const bf16_t* bp = (kn < 8 ? Ubf : Wbf) + (size_t)tid * E_DIM + (kn & 7) * 32;
            br0 = *(const bf16x8*)(bp);
            br1 = *(const bf16x8*)(bp + 8);
            br2 = *(const bf16x8*)(bp + 16);
            br3 = *(const bf16x8*)(bp + 24);
        }
        bf16x8 af;
        f32x4 n0, n1;
        if (kc < 8) {                          // state part + fp32 gate dot
            f32x4 xv0 = *(const f32x4*)(xp + kc * 32);
            f32x4 xv1 = *(const f32x4*)(xp + kc * 32 + 4);
            if (kc < 7) {                      // prefetch next A chunk
                n0 = *(const f32x4*)(sp + (kc + 1) * 32);
                n1 = *(const f32x4*)(sp + (kc + 1) * 32 + 4);
            }
#pragma unroll
            for (int i = 0; i < 4; ++i) { af[i] = (bf16_t)a0[i]; af[4 + i] = (bf16_t)a1[i]; }
#pragma unroll
            for (int i = 0; i < 4; ++i) gdot += a0[i] * xv0[i];
#pragma unroll
            for (int i = 0; i < 4; ++i) gdot += a1[i] * xv1[i];
        } else {                               // x part: broadcast row of b
            const float* xq = xp + (kc - 8) * 32;
            f32x4 xa = *(const f32x4*)xq;
            f32x4 xb = *(const f32x4*)(xq + 4);
#pragma unroll
            for (int i = 0; i < 4; ++i) { af[i] = (bf16_t)xa[i]; af[4 + i] = (bf16_t)xb[i]; }
        }
#pragma unroll
        for (int nt = 0; nt < 16; ++nt) {
            bf16x8 bfr = *(const bf16x8*)(&sB[cur][nt * 16 + l15][quad * 8]);
            acc[nt] = __builtin_amdgcn_mfma_f32_16x16x32_bf16(af, bfr, acc[nt], 0, 0, 0);
        }
        if (kc < 8) { a0 = n0; a1 = n1; }
        // write prefetched tile into the other buffer, then single barrier
        if (kc < 15) {
            *(bf16x8*)(&sB[cur ^ 1][tid][0])  = br0;
            *(bf16x8*)(&sB[cur ^ 1][tid][8])  = br1;
            *(bf16x8*)(&sB[cur ^ 1][tid][16]) = br2;
            *(bf16x8*)(&sB[cur ^ 1][tid][24]) = br3;
            __syncthreads();
        }
    }

    // reduce gate dot across quads (k was split quad-wise)
    gdot += __shfl_xor(gdot, 16);
    gdot += __shfl_xor(gdot, 32);
    float garg = gdot + xk[(size_t)bw * J_DIM + (w & 1) * 16 + l15];
    float gv = 1.f / (1.f + expf(-garg));
    float gate[4];
#pragma unroll
    for (int r = 0; r < 4; ++r) gate[r] = __shfl(gv, quad * 4 + r);
    // epilogue: C/D layout row = quad*4+r, col = nt*16+l15
    float sumsq[4] = {0.f, 0.f, 0.f, 0.f};
#pragma unroll
    for (int nt = 0; nt < 16; ++nt) {
        int f = nt * 16 + l15;
#pragma unroll
        for (int r = 0; r < 4; ++r) {
            int rl = quad * 4 + r;
            int jidx = (w & 1) * 16 + rl;
            float c = acc[nt][r] + vkb[(size_t)jidx * E_DIM + f];
            c = fmaxf(c, 0.f);
            float sv = state[(size_t)(m0 + w * 16 + rl) * E_DIM + f]; // LLC-hot re-read
            float t = fmaf(gate[r], c, sv);
            acc[nt][r] = t;
            sumsq[r] += t * t;
        }
    }
    float rn[4];
#pragma unroll
    for (int r = 0; r < 4; ++r) {
        float s2 = sumsq[r];
        s2 += __shfl_xor(s2, 1);
        s2 += __shfl_xor(s2, 2);
        s2 += __shfl_xor(s2, 4);
        s2 += __shfl_xor(s2, 8);
        rn[r] = 1.f / (sqrtf(s2) + 1e-8f);
    }
#pragma unroll
    for (int nt = 0; nt < 16; ++nt)
#pragma unroll
        for (int r = 0; r < 4; ++r)
            out[(size_t)(m0 + w * 16 + quad * 4 + r) * E_DIM + nt * 16 + l15] =
                acc[nt][r] * rn[r];
}

extern "C" void kernel_launch(void* const* d_in, const int* in_sizes, int n_in,
                              void* d_out, int out_size, void* d_ws, size_t ws_size,
                              hipStream_t stream) {
    const float* x     = (const float*)d_in[0];
    const float* state = (const float*)d_in[1];
    const float* keys  = (const float*)d_in[2];
    const float* U     = (const float*)d_in[3];
    const float* V     = (const float*)d_in[4];
    const float* W     = (const float*)d_in[5];
    const float* bias  = (const float*)d_in[6];
    float* out = (float*)d_out;

    float* wsf = (float*)d_ws;
    float* xk  = wsf;                                     // 4096*32 fp32 = 512 KB
    float* vkb = xk + (size_t)B_DIM * J_DIM;              // 32*256  fp32 = 32 KB
    bf16_t* Ubf = (bf16_t*)(vkb + (size_t)J_DIM * E_DIM); // 256*256 bf16 = 128 KB
    bf16_t* Wbf = Ubf + (size_t)E_DIM * E_DIM;            // 256*256 bf16 = 128 KB

    prep_kernel<<<PREP_GRID, 256, 0, stream>>>(x, keys, U, V, W, bias, xk, vkb, Ubf, Wbf);
    memcell_kernel<<<M_DIM / 64, 256, 0, stream>>>(x, state, Ubf, Wbf, xk, vkb, out);
}